// Round 13
// baseline (416.038 us; speedup 1.0000x reference)
//
#include <hip/hip_runtime.h>
#include <hip/hip_bf16.h>
#include <math.h>

#define H 128
#define K 20
#define EPB 16        // edges per block (M=16 for MFMA)

// ---- workspace layout (float offsets) ----
// Sign-folded table: rows 2r+s (s=sign bit), r in [0, M] with M <= 128
// (M = #nonzero tp_w1 entries <= H). 258 rows x 256 floats = 66048.
#define WS_TBL    0            // merged table: 258 rows x 256 floats {W, B+se}
#define WS_THM    66048        // 128 merged sorted thresholds (M <= 128)
#define WS_CNT    66432        // 1 int: M = nP + nN
#define WSB_HI    67072        // 65536 ushort: em_w1 bf16-hi, B-fragment order
#define WSB_LO    99840        // 65536 ushort: em_w1 bf16-lo

typedef __attribute__((ext_vector_type(8))) short short8;
typedef __attribute__((ext_vector_type(4))) float f32x4;

// DPP-based wave64 sum; result valid in lane 63. (used by MLP tail)
template<int CTRL, int RMASK>
__device__ __forceinline__ float dpp_add(float x) {
  int y = __builtin_amdgcn_update_dpp(0, __float_as_int(x), CTRL, RMASK, 0xf, true);
  return x + __int_as_float(y);
}
__device__ __forceinline__ float wave_sum63(float x) {
  x = dpp_add<0xB1,  0xf>(x);
  x = dpp_add<0x4E,  0xf>(x);
  x = dpp_add<0x141, 0xf>(x);
  x = dpp_add<0x140, 0xf>(x);
  x = dpp_add<0x142, 0xa>(x);
  x = dpp_add<0x143, 0xc>(x);
  return x;
}
__device__ __forceinline__ float bcast63(float x) {
  return __int_as_float(__builtin_amdgcn_readlane(__float_as_int(x), 63));
}

// DPP lane-permute mov (full row/bank masks, bound_ctrl=1)
template<int CTRL>
__device__ __forceinline__ float dpp_mov(float x) {
  return __int_as_float(
      __builtin_amdgcn_update_dpp(0, __float_as_int(x), CTRL, 0xf, 0xf, true));
}
template<int L>
__device__ __forceinline__ float rdlane(float x) {
  return __int_as_float(__builtin_amdgcn_readlane(__float_as_int(x), L));
}
// Crossed-select merge (verified on HW in R5): out[l] = Z_b[l] + Z_b[l^1],
// b = beta(l); requires beta(l^1) != beta(l).
template<int CTRL>
__device__ __forceinline__ float merge2(float z0, float z1, bool beta) {
  float keep = beta ? z1 : z0;
  float sel  = beta ? z0 : z1;
  return keep + dpp_mov<CTRL>(sel);
}
// Joint 2-key all-lane reduction keeping chains independent:
// even lanes end with key0's full 64-lane sum, odd lanes key1's.
__device__ __forceinline__ float red2(float z0, float z1, bool b0) {
  float r = merge2<0xB1>(z0, z1, b0);   // quad_perm xor1 (crossed-select)
  r += dpp_mov<0x4E>(r);                // quad_perm xor2
  r += dpp_mov<0x124>(r);               // row_ror:4
  r += dpp_mov<0x128>(r);               // row_ror:8
  r += __shfl_xor(r, 16);
  r += __shfl_xor(r, 32);
  return r;
}

// Async global->LDS DMA (documented builtin, HW-verified m03/m97).
// Per-lane global src; wave-uniform LDS base; HW writes lds[base + lane*16].
// NO VGPR destination -> the register allocator cannot serialize the batch.
__device__ __forceinline__ void dma_row16(const float* gsrc, float* lds) {
  __builtin_amdgcn_global_load_lds(
      (const __attribute__((address_space(1))) unsigned int*)
          ((const __attribute__((address_space(1))) void*)gsrc),
      (__attribute__((address_space(3))) unsigned int*)
          ((__attribute__((address_space(3))) void*)lds),
      16, 0, 0);
}

__device__ __forceinline__ unsigned short bfbits(float x) {
  __hip_bfloat16 h = __float2bfloat16(x);
  unsigned short u; __builtin_memcpy(&u, &h, 2); return u;
}
__device__ __forceinline__ float bf2f(unsigned short u) {
  return __uint_as_float(((unsigned)u) << 16);
}

// Single fused aux kernel (769 blocks x 128 threads):
//  blocks 0..256  : locally recompute the threshold sort, then build the
//                   SIGN-FOLDED merged-table rows 2r / 2r+1 (block 0 also
//                   publishes THM/CNT). Row 2r+s = {W, B + sign_emb[s]}.
//  blocks 257..768: pack em_w1 into bf16 hi/lo planes, B-fragment order.
__global__ __launch_bounds__(128) void aux_kernel(
    const float* __restrict__ w1v, const float* __restrict__ b1v,
    const float* __restrict__ w2, const float* __restrict__ b2,
    const float* __restrict__ se, const float* __restrict__ em_w1,
    float* __restrict__ ws)
{
  int blk = blockIdx.x;
  int tid = threadIdx.x;
  if (blk < 257) {
    __shared__ float th[H];
    __shared__ int grp[H];
    __shared__ int sidx[2 * H];
    __shared__ int Msh;
    float w = w1v[tid], b = b1v[tid];
    int g = (w > 0.f) ? 0 : ((w < 0.f) ? 1 : 2);   // 0=P, 1=N, 2=Z
    float t = (g == 2) ? 0.f : (-b / w);
    th[tid] = t; grp[tid] = g;
    if (tid == 0) Msh = 0;
    __syncthreads();
    if (g != 2) {
      int r = 0;
      for (int i = 0; i < H; i++)
        if (grp[i] != 2 && (th[i] < t || (th[i] == t && i < tid))) r++;
      sidx[r] = (tid << 1) | (g == 0 ? 1 : 0);     // bit0 = isP
      atomicAdd(&Msh, 1);
      if (blk == 0) ws[WS_THM + r] = t;            // publish for main
    }
    __syncthreads();
    int M = Msh;                                   // M <= H = 128
    if (blk == 0 && tid == 0) ((int*)(ws + WS_CNT))[0] = M;
    int r = blk;
    if (r > M) return;
    int d = tid;
    // BASE[d] = tp_b2[d] + sum over (w1==0, b1>0) of b1*w2[h][d]
    float accW = 0.f, accB = b2[d];
    for (int i = 0; i < H; i++)
      if (grp[i] == 2 && b1v[i] > 0.f) accB += b1v[i] * w2[i * H + d];
    #pragma unroll 4
    for (int i = 0; i < M; i++) {
      int ent = sidx[i];
      int h = ent >> 1;
      int isP = ent & 1;
      int take = (i < r) ? isP : (1 - isP);
      if (take) {
        float wv = w2[h * H + d];
        accW += w1v[h] * wv;
        accB += b1v[h] * wv;
      }
    }
    // sign-folded rows
    ws[WS_TBL + (2 * r + 0) * 256 + 2 * d + 0] = accW;
    ws[WS_TBL + (2 * r + 0) * 256 + 2 * d + 1] = accB + se[d];
    ws[WS_TBL + (2 * r + 1) * 256 + 2 * d + 0] = accW;
    ws[WS_TBL + (2 * r + 1) * 256 + 2 * d + 1] = accB + se[H + d];
  } else {
    // pack: B-fragment for mfma_f32_16x16x32_bf16:
    // frag (c,kc,lane) elem j = B[k=kc*32+(lane>>4)*8+j][n=c*16+(lane&15)]
    int idx = (blk - 257) * 128 + tid;             // 65536 total
    int j  = idx & 7;
    int l  = (idx >> 3) & 63;
    int kc = (idx >> 9) & 15;
    int c  = idx >> 13;
    int k = kc * 32 + ((l >> 4) * 8) + j;
    int n = c * 16 + (l & 15);
    float x = em_w1[k * H + n];
    unsigned short hb = bfbits(x);
    unsigned short lb = bfbits(x - bf2f(hb));
    ((unsigned short*)(ws + WSB_HI))[idx] = hb;
    ((unsigned short*)(ws + WSB_LO))[idx] = lb;
  }
}

// Attention: each wave owns 4 EDGES; both sides (u,v) concurrently, FOUR keys
// per side per iteration, straight-line select-guarded body.
// sign_emb folded into the table rows; log2-space softmax (raw exp2).
// R13: the 8 TABLE-row gathers are async global->LDS DMAs (no VGPR dest ->
// the allocator cannot serialize them; R4-R12 showed compiler-issued batched
// loads get serialized one-latency-at-a-time at VGPR=52). 8 emb loads stay
// as plain loads (only 16 dest regs, now with slack). One vmcnt(0) drain.
__device__ __forceinline__ void run_sides(
    int sbase, int b0, int B, int lane,
    const int* __restrict__ edge_index, const int* __restrict__ edge_ts,
    const int* __restrict__ hist_nb, const int* __restrict__ hist_tm,
    const int* __restrict__ hist_sg,
    const float* __restrict__ node_emb, const float* __restrict__ ws,
    float th0, float th1, float* __restrict__ zbuf, float* __restrict__ stg)
{
  // 1/sqrt(128) * log2(e): scores computed directly in log2 space
  const float S = 0.088388347648318447f * 1.4426950408889634f;
  const bool b0sel = (lane & 1) != 0;
  int eBase = sbase >> 1;                  // 4 edges per wave
  // ---- prefetch edge eBase (both sides) ----
  int eN = b0 + eBase;
  int nU = edge_index[eN];
  int nV = edge_index[B + eN];
  int t_n = edge_ts[eN];
  float2 qU_n = *(const float2*)(node_emb + (size_t)nU * H + 2 * lane);
  float2 qV_n = *(const float2*)(node_emb + (size_t)nV * H + 2 * lane);
  int pkU_n = 0, tmU_n = 0, pkV_n = 0, tmV_n = 0;
  if (lane < K) {
    pkU_n = (hist_nb[nU * K + lane] << 1) | hist_sg[nU * K + lane];
    tmU_n = hist_tm[nU * K + lane];
    pkV_n = (hist_nb[nV * K + lane] << 1) | hist_sg[nV * K + lane];
    tmV_n = hist_tm[nV * K + lane];
  }

  #pragma unroll 1
  for (int p = 0; p < 4; p++) {
    int e = eBase + p;
    int tC = t_n;
    float2 qU = qU_n, qV = qV_n;
    int pkU = pkU_n, tmU = tmU_n, pkV = pkV_n, tmV = tmV_n;
    if (p < 3) {
      int e2 = b0 + e + 1;
      int nU2 = edge_index[e2];
      int nV2 = edge_index[B + e2];
      t_n = edge_ts[e2];
      qU_n = *(const float2*)(node_emb + (size_t)nU2 * H + 2 * lane);
      qV_n = *(const float2*)(node_emb + (size_t)nV2 * H + 2 * lane);
      if (lane < K) {
        pkU_n = (hist_nb[nU2 * K + lane] << 1) | hist_sg[nU2 * K + lane];
        tmU_n = hist_tm[nU2 * K + lane];
        pkV_n = (hist_nb[nV2 * K + lane] << 1) | hist_sg[nV2 * K + lane];
        tmV_n = hist_tm[nV2 * K + lane];
      }
    }

    unsigned long long mU0 = __ballot((lane < K) && (tmU < tC) && (pkU >= 0));
    unsigned long long mV0 = __ballot((lane < K) && (tmV < tC) && (pkV >= 0));
    bool fU = (mU0 == 0), fV = (mV0 == 0);
    unsigned long long mU = fU ? 0xFFFFFull : mU0;
    unsigned long long mV = fV ? 0xFFFFFull : mV0;
    float qUx = qU.x * S, qUy = qU.y * S;
    float qVx = qV.x * S, qVy = qV.y * S;

    float mxU = -3.0e38f, ssU = 0.f, zU0 = 0.f, zU1 = 0.f;
    float mxV = -3.0e38f, ssV = 0.f, zV0 = 0.f, zV1 = 0.f;

    #define RANK2(d) (__popcll(__ballot(th0 < (d))) + __popcll(__ballot(th1 < (d))))

    while (mU | mV) {
      // ---- pop 4 slots per side (SALU chain, cheap)
      bool vUa = mU != 0; int kUa = vUa ? __ffsll((long long)mU) - 1 : 0; mU &= mU - 1;
      bool vUb = mU != 0; int kUb = vUb ? __ffsll((long long)mU) - 1 : 0; mU &= mU - 1;
      bool vUc = mU != 0; int kUc = vUc ? __ffsll((long long)mU) - 1 : 0; mU &= mU - 1;
      bool vUd = mU != 0; int kUd = vUd ? __ffsll((long long)mU) - 1 : 0; mU &= mU - 1;
      bool vVa = mV != 0; int kVa = vVa ? __ffsll((long long)mV) - 1 : 0; mV &= mV - 1;
      bool vVb = mV != 0; int kVb = vVb ? __ffsll((long long)mV) - 1 : 0; mV &= mV - 1;
      bool vVc = mV != 0; int kVc = vVc ? __ffsll((long long)mV) - 1 : 0; mV &= mV - 1;
      bool vVd = mV != 0; int kVd = vVd ? __ffsll((long long)mV) - 1 : 0; mV &= mV - 1;

      // ---- metadata (readlane -> wave-uniform)
      int tmUa = __builtin_amdgcn_readlane(tmU, kUa), pkUa = __builtin_amdgcn_readlane(pkU, kUa);
      int tmUb = __builtin_amdgcn_readlane(tmU, kUb), pkUb = __builtin_amdgcn_readlane(pkU, kUb);
      int tmUc = __builtin_amdgcn_readlane(tmU, kUc), pkUc = __builtin_amdgcn_readlane(pkU, kUc);
      int tmUd = __builtin_amdgcn_readlane(tmU, kUd), pkUd = __builtin_amdgcn_readlane(pkU, kUd);
      int tmVa = __builtin_amdgcn_readlane(tmV, kVa), pkVa = __builtin_amdgcn_readlane(pkV, kVa);
      int tmVb = __builtin_amdgcn_readlane(tmV, kVb), pkVb = __builtin_amdgcn_readlane(pkV, kVb);
      int tmVc = __builtin_amdgcn_readlane(tmV, kVc), pkVc = __builtin_amdgcn_readlane(pkV, kVc);
      int tmVd = __builtin_amdgcn_readlane(tmV, kVd), pkVd = __builtin_amdgcn_readlane(pkV, kVd);

      float dUa = (float)(tC - tmUa), dUb = (float)(tC - tmUb);
      float dUc = (float)(tC - tmUc), dUd = (float)(tC - tmUd);
      float dVa = (float)(tC - tmVa), dVb = (float)(tC - tmVb);
      float dVc = (float)(tC - tmVc), dVd = (float)(tC - tmVd);

      // sign-folded table row index (wave-uniform scalar arithmetic)
      int rUa = 2 * RANK2(dUa) + (pkUa & 1), rUb = 2 * RANK2(dUb) + (pkUb & 1);
      int rUc = 2 * RANK2(dUc) + (pkUc & 1), rUd = 2 * RANK2(dUd) + (pkUd & 1);
      int rVa = 2 * RANK2(dVa) + (pkVa & 1), rVb = 2 * RANK2(dVb) + (pkVb & 1);
      int rVc = 2 * RANK2(dVc) + (pkVc & 1), rVd = 2 * RANK2(dVd) + (pkVd & 1);

      // ---- 8 async table-row DMAs (no VGPR dest -> all in flight)
      dma_row16(ws + WS_TBL + rUa * 256 + 4 * lane, stg + 0 * 256);
      dma_row16(ws + WS_TBL + rUb * 256 + 4 * lane, stg + 1 * 256);
      dma_row16(ws + WS_TBL + rUc * 256 + 4 * lane, stg + 2 * 256);
      dma_row16(ws + WS_TBL + rUd * 256 + 4 * lane, stg + 3 * 256);
      dma_row16(ws + WS_TBL + rVa * 256 + 4 * lane, stg + 4 * 256);
      dma_row16(ws + WS_TBL + rVb * 256 + 4 * lane, stg + 5 * 256);
      dma_row16(ws + WS_TBL + rVc * 256 + 4 * lane, stg + 6 * 256);
      dma_row16(ws + WS_TBL + rVd * 256 + 4 * lane, stg + 7 * 256);
      // ---- 8 embedding loads (16 dest VGPRs, now with allocator slack)
      float2 neUa = *(const float2*)(node_emb + (size_t)(pkUa >> 1) * H + 2 * lane);
      float2 neUb = *(const float2*)(node_emb + (size_t)(pkUb >> 1) * H + 2 * lane);
      float2 neUc = *(const float2*)(node_emb + (size_t)(pkUc >> 1) * H + 2 * lane);
      float2 neUd = *(const float2*)(node_emb + (size_t)(pkUd >> 1) * H + 2 * lane);
      float2 neVa = *(const float2*)(node_emb + (size_t)(pkVa >> 1) * H + 2 * lane);
      float2 neVb = *(const float2*)(node_emb + (size_t)(pkVb >> 1) * H + 2 * lane);
      float2 neVc = *(const float2*)(node_emb + (size_t)(pkVc >> 1) * H + 2 * lane);
      float2 neVd = *(const float2*)(node_emb + (size_t)(pkVd >> 1) * H + 2 * lane);
      // single drain for DMAs + emb; sched_barrier stops hoisting (rule #18)
      asm volatile("s_waitcnt vmcnt(0)" ::: "memory");
      __builtin_amdgcn_sched_barrier(0);

      // ---- read staged table rows from LDS (short latency, lgkmcnt)
      const float4 tbUa = *(const float4*)(stg + 0 * 256 + 4 * lane);
      const float4 tbUb = *(const float4*)(stg + 1 * 256 + 4 * lane);
      const float4 tbUc = *(const float4*)(stg + 2 * 256 + 4 * lane);
      const float4 tbUd = *(const float4*)(stg + 3 * 256 + 4 * lane);
      const float4 tbVa = *(const float4*)(stg + 4 * 256 + 4 * lane);
      const float4 tbVb = *(const float4*)(stg + 5 * 256 + 4 * lane);
      const float4 tbVc = *(const float4*)(stg + 6 * 256 + 4 * lane);
      const float4 tbVd = *(const float4*)(stg + 7 * 256 + 4 * lane);

      // ---- build keys: k = ne + (d*W + B')   (2 ops per dim)
      float kU0a = neUa.x + (dUa * tbUa.x + tbUa.y);
      float kU1a = neUa.y + (dUa * tbUa.z + tbUa.w);
      float kU0b = neUb.x + (dUb * tbUb.x + tbUb.y);
      float kU1b = neUb.y + (dUb * tbUb.z + tbUb.w);
      float kU0c = neUc.x + (dUc * tbUc.x + tbUc.y);
      float kU1c = neUc.y + (dUc * tbUc.z + tbUc.w);
      float kU0d = neUd.x + (dUd * tbUd.x + tbUd.y);
      float kU1d = neUd.y + (dUd * tbUd.z + tbUd.w);
      float kV0a = neVa.x + (dVa * tbVa.x + tbVa.y);
      float kV1a = neVa.y + (dVa * tbVa.z + tbVa.w);
      float kV0b = neVb.x + (dVb * tbVb.x + tbVb.y);
      float kV1b = neVb.y + (dVb * tbVb.z + tbVb.w);
      float kV0c = neVc.x + (dVc * tbVc.x + tbVc.y);
      float kV1c = neVc.y + (dVc * tbVc.z + tbVc.w);
      float kV0d = neVd.x + (dVd * tbVd.x + tbVd.y);
      float kV1d = neVd.y + (dVd * tbVd.z + tbVd.w);

      // ---- dot partials + 4 independent pairwise reductions
      float p0 = qUx * kU0a + qUy * kU1a;
      float p1 = qUx * kU0b + qUy * kU1b;
      float p2 = qUx * kU0c + qUy * kU1c;
      float p3 = qUx * kU0d + qUy * kU1d;
      float p4 = qVx * kV0a + qVy * kV1a;
      float p5 = qVx * kV0b + qVy * kV1b;
      float p6 = qVx * kV0c + qVy * kV1c;
      float p7 = qVx * kV0d + qVy * kV1d;
      float cU01 = red2(p0, p1, b0sel);
      float cU23 = red2(p2, p3, b0sel);
      float cV01 = red2(p4, p5, b0sel);
      float cV23 = red2(p6, p7, b0sel);

      float sUa = vUa ? (fU ? -1e9f : rdlane<0>(cU01)) : -3.0e38f;
      float sUb = vUb ? (fU ? -1e9f : rdlane<1>(cU01)) : -3.0e38f;
      float sUc = vUc ? (fU ? -1e9f : rdlane<0>(cU23)) : -3.0e38f;
      float sUd = vUd ? (fU ? -1e9f : rdlane<1>(cU23)) : -3.0e38f;
      float sVa = vVa ? (fV ? -1e9f : rdlane<0>(cV01)) : -3.0e38f;
      float sVb = vVb ? (fV ? -1e9f : rdlane<1>(cV01)) : -3.0e38f;
      float sVc = vVc ? (fV ? -1e9f : rdlane<0>(cV23)) : -3.0e38f;
      float sVd = vVd ? (fV ? -1e9f : rdlane<1>(cV23)) : -3.0e38f;

      // ---- 4-wide online-max softmax accumulate (log2 space, raw exp2)
      float mnU = fmaxf(fmaxf(mxU, fmaxf(sUa, sUb)), fmaxf(sUc, sUd));
      float alU = exp2f(mxU - mnU);
      float wUa = exp2f(sUa - mnU), wUb = exp2f(sUb - mnU);
      float wUc = exp2f(sUc - mnU), wUd = exp2f(sUd - mnU);
      ssU = ssU * alU + ((wUa + wUb) + (wUc + wUd));
      zU0 = zU0 * alU + ((wUa * kU0a + wUb * kU0b) + (wUc * kU0c + wUd * kU0d));
      zU1 = zU1 * alU + ((wUa * kU1a + wUb * kU1b) + (wUc * kU1c + wUd * kU1d));
      mxU = mnU;

      float mnV = fmaxf(fmaxf(mxV, fmaxf(sVa, sVb)), fmaxf(sVc, sVd));
      float alV = exp2f(mxV - mnV);
      float wVa = exp2f(sVa - mnV), wVb = exp2f(sVb - mnV);
      float wVc = exp2f(sVc - mnV), wVd = exp2f(sVd - mnV);
      ssV = ssV * alV + ((wVa + wVb) + (wVc + wVd));
      zV0 = zV0 * alV + ((wVa * kV0a + wVb * kV0b) + (wVc * kV0c + wVd * kV0d));
      zV1 = zV1 * alV + ((wVa * kV1a + wVb * kV1b) + (wVc * kV1c + wVd * kV1d));
      mxV = mnV;
    }
    #undef RANK2

    // unified normalize: fallback sides have ss == 20.0 exactly
    float invU = 1.f / ssU; zU0 *= invU; zU1 *= invU;
    float invV = 1.f / ssV; zV0 *= invV; zV1 *= invV;

    int sw = (e & 7) << 1;
    int ccU = lane ^ sw;
    int ccV = (64 + lane) ^ sw;
    *(float2*)&zbuf[(e << 8) + (ccU << 1)] = make_float2(zU0, zU1);
    *(float2*)&zbuf[(e << 8) + (ccV << 1)] = make_float2(zV0, zV1);
  }
}

// Main fused kernel: 4 waves/block, each wave owns 4 edges (8 sides) with
// dual-side + quad-key ILP, table gathers via async global->LDS DMA (32 KB
// staging), pairwise reductions, sign-folded table, log2-space softmax.
// 48 KB LDS/block -> 3 blocks/CU = 12 waves/CU (matches achieved occupancy).
__global__ __launch_bounds__(256, 3) void tgat_main_kernel(
    const int* __restrict__ edge_index, const int* __restrict__ edge_ts,
    const int* __restrict__ hist_nb, const int* __restrict__ hist_tm,
    const int* __restrict__ hist_sg,
    const float* __restrict__ node_emb,
    const float* __restrict__ em_b1,
    const float* __restrict__ em_w2, const float* __restrict__ em_b2,
    const float* __restrict__ ws, float* __restrict__ out, int B)
{
  // zbuf rows = 16 edges, 256 floats (zu|zv) per row, float2-chunk XOR swizzle:
  // logical chunk c of row e stored at chunk c ^ ((e&7)<<1). 16 KB total.
  __shared__ __align__(16) float zbuf[EPB * 256];
  // per-wave table staging: 8 rows x 256 floats (1 KB each), 32 KB total
  __shared__ __align__(16) float stage[4 * 8 * 256];

  int tid = threadIdx.x;
  int lane = tid & 63;
  int wv = __builtin_amdgcn_readfirstlane(tid >> 6);
  int b0 = blockIdx.x * EPB;

  int M = ((const int*)(ws + WS_CNT))[0];   // M <= 128 always
  float th0 = (lane       < M) ? ws[WS_THM + lane      ] : 3.0e38f;
  float th1 = (lane + 64  < M) ? ws[WS_THM + lane + 64 ] : 3.0e38f;

  int sbase = wv * 8;
  run_sides(sbase, b0, B, lane, edge_index, edge_ts, hist_nb, hist_tm,
            hist_sg, node_emb, ws, th0, th1, zbuf, stage + wv * 2048);
  __syncthreads();

  // ---- MLP layer 1 via split-bf16 MFMA: hid[16][128] = feat[16][512] @ em_w1
  // feat regions: [zu | zv | |zu-zv| | zu*zv], built on the fly from zbuf.
  const unsigned short* whi = (const unsigned short*)(ws + WSB_HI);
  const unsigned short* wlo = (const unsigned short*)(ws + WSB_LO);
  int c0 = 2 * wv;
  int m_ = lane & 15;
  int qd = lane >> 4;
  int sw = (m_ & 7) << 1;
  const float* zrow = zbuf + (m_ << 8);
  f32x4 acc0 = {0.f, 0.f, 0.f, 0.f};
  f32x4 acc1 = {0.f, 0.f, 0.f, 0.f};
  #pragma unroll
  for (int kc = 0; kc < 16; kc++) {
    const int reg = kc >> 2;
    int cb = (kc & 3) * 16 + qd * 4;     // base chunk within a 128-dim region
    float av[8];
    if (reg == 0) {
      float4 A0 = *(const float4*)(zrow + (((cb    ) ^ sw) << 1));
      float4 A1 = *(const float4*)(zrow + (((cb + 2) ^ sw) << 1));
      av[0]=A0.x; av[1]=A0.y; av[2]=A0.z; av[3]=A0.w;
      av[4]=A1.x; av[5]=A1.y; av[6]=A1.z; av[7]=A1.w;
    } else if (reg == 1) {
      float4 A0 = *(const float4*)(zrow + (((cb + 64) ^ sw) << 1));
      float4 A1 = *(const float4*)(zrow + (((cb + 66) ^ sw) << 1));
      av[0]=A0.x; av[1]=A0.y; av[2]=A0.z; av[3]=A0.w;
      av[4]=A1.x; av[5]=A1.y; av[6]=A1.z; av[7]=A1.w;
    } else {
      float4 U0 = *(const float4*)(zrow + (((cb    ) ^ sw) << 1));
      float4 U1 = *(const float4*)(zrow + (((cb + 2) ^ sw) << 1));
      float4 V0 = *(const float4*)(zrow + (((cb + 64) ^ sw) << 1));
      float4 V1 = *(const float4*)(zrow + (((cb + 66) ^ sw) << 1));
      float uu[8] = {U0.x,U0.y,U0.z,U0.w,U1.x,U1.y,U1.z,U1.w};
      float vvv[8] = {V0.x,V0.y,V0.z,V0.w,V1.x,V1.y,V1.z,V1.w};
      if (reg == 2) {
        #pragma unroll
        for (int j = 0; j < 8; j++) av[j] = fabsf(uu[j] - vvv[j]);
      } else {
        #pragma unroll
        for (int j = 0; j < 8; j++) av[j] = uu[j] * vvv[j];
      }
    }
    // split-bf16 A fragments: hi = bit-truncation (v_perm pack, 1 op/pair),
    // lo = exact residual (Sterbenz) rounded-ne as a packed pair.
    union { short8 v; unsigned u[4]; } ahi, alo;
    #pragma unroll
    for (int j = 0; j < 4; j++) {
      unsigned b0u = __float_as_uint(av[2 * j]);
      unsigned b1u = __float_as_uint(av[2 * j + 1]);
      ahi.u[j] = __builtin_amdgcn_perm(b1u, b0u, 0x07060302u);
      float l0 = av[2 * j]     - __uint_as_float(b0u & 0xFFFF0000u);
      float l1 = av[2 * j + 1] - __uint_as_float(b1u & 0xFFFF0000u);
      __hip_bfloat162 lp = __float22bfloat162_rn(make_float2(l0, l1));
      __builtin_memcpy(&alo.u[j], &lp, 4);
    }
    int f0 = (((c0    ) * 16 + kc) * 64 + lane) * 8;
    int f1 = (((c0 + 1) * 16 + kc) * 64 + lane) * 8;
    short8 bh0 = *(const short8*)(whi + f0);
    short8 bl0 = *(const short8*)(wlo + f0);
    short8 bh1 = *(const short8*)(whi + f1);
    short8 bl1 = *(const short8*)(wlo + f1);
    acc0 = __builtin_amdgcn_mfma_f32_16x16x32_bf16(ahi.v, bh0, acc0, 0, 0, 0);
    acc0 = __builtin_amdgcn_mfma_f32_16x16x32_bf16(ahi.v, bl0, acc0, 0, 0, 0);
    acc0 = __builtin_amdgcn_mfma_f32_16x16x32_bf16(alo.v, bh0, acc0, 0, 0, 0);
    acc1 = __builtin_amdgcn_mfma_f32_16x16x32_bf16(ahi.v, bh1, acc1, 0, 0, 0);
    acc1 = __builtin_amdgcn_mfma_f32_16x16x32_bf16(ahi.v, bl1, acc1, 0, 0, 0);
    acc1 = __builtin_amdgcn_mfma_f32_16x16x32_bf16(alo.v, bh1, acc1, 0, 0, 0);
  }
  __syncthreads();   // all A-reads of zbuf complete before overlay reuse

  // bias + relu, write hid into zbuf overlay (stride 132)
  float* hp = zbuf;
  float eb0 = em_b1[c0 * 16 + m_];
  float eb1 = em_b1[(c0 + 1) * 16 + m_];
  #pragma unroll
  for (int r = 0; r < 4; r++) {
    int edge = qd * 4 + r;
    hp[edge * 132 + c0 * 16 + m_]       = fmaxf(acc0[r] + eb0, 0.f);
    hp[edge * 132 + (c0 + 1) * 16 + m_] = fmaxf(acc1[r] + eb1, 0.f);
  }
  __syncthreads();

  // ---- layer 2: logits = hid @ em_w2 + em_b2 ; wave wv does edges wv*4..+3
  float2 w2v = *(const float2*)(em_w2 + 2 * lane);
  float bias2 = em_b2[0];
  #pragma unroll
  for (int i = 0; i < 4; i++) {
    int e = wv * 4 + i;
    int b = b0 + e;
    float2 hv = *(const float2*)(hp + e * 132 + 2 * lane);
    float p = wave_sum63(hv.x * w2v.x + hv.y * w2v.y);
    float ps = bcast63(p);
    if (lane == 0 && b < B) out[b] = ps + bias2;
  }
}

extern "C" void kernel_launch(void* const* d_in, const int* in_sizes, int n_in,
                              void* d_out, int out_size, void* d_ws, size_t ws_size,
                              hipStream_t stream)
{
  (void)n_in; (void)out_size; (void)ws_size;
  const int* edge_index = (const int*)d_in[0];
  const int* edge_ts    = (const int*)d_in[1];
  const int* hist_nb    = (const int*)d_in[2];
  const int* hist_tm    = (const int*)d_in[3];
  const int* hist_sg    = (const int*)d_in[4];
  const float* node_emb = (const float*)d_in[5];
  const float* sign_emb = (const float*)d_in[6];
  const float* tp_w1    = (const float*)d_in[7];
  const float* tp_b1    = (const float*)d_in[8];
  const float* tp_w2    = (const float*)d_in[9];
  const float* tp_b2    = (const float*)d_in[10];
  const float* em_w1    = (const float*)d_in[11];
  const float* em_b1    = (const float*)d_in[12];
  const float* em_w2    = (const float*)d_in[13];
  const float* em_b2    = (const float*)d_in[14];
  float* out = (float*)d_out;
  float* ws  = (float*)d_ws;
  int B = in_sizes[1];

  hipLaunchKernelGGL(aux_kernel, dim3(769), dim3(128), 0, stream,
                     tp_w1, tp_b1, tp_w2, tp_b2, sign_emb, em_w1, ws);
  int grid = (B + EPB - 1) / EPB;
  hipLaunchKernelGGL(tgat_main_kernel, dim3(grid), dim3(256), 0, stream,
                     edge_index, edge_ts, hist_nb, hist_tm, hist_sg,
                     node_emb, em_b1, em_w2, em_b2, ws, out, B);
}

// Round 14
// 341.161 us; speedup vs baseline: 1.2195x; 1.2195x over previous
//
#include <hip/hip_runtime.h>
#include <hip/hip_bf16.h>
#include <math.h>

#define H 128
#define K 20
#define EPB 16        // edges per block (M=16 for MFMA)

// ---- workspace layout (float offsets) ----
#define WSB_HI    67072        // 65536 ushort: em_w1 bf16-hi, B-fragment order
#define WSB_LO    99840        // 65536 ushort: em_w1 bf16-lo
#define W2T_HI    132608       // 16384 ushort: w2^T hi (G = Qs @ w2^T)
#define W2T_LO    140800       // 16384 ushort: w2^T lo
#define W2_HI     148992       // 16384 ushort: w2 hi   (ZT = Y @ w2)
#define W2_LO     157184       // 16384 ushort: w2 lo

// scale: 1/sqrt(128) * log2(e)  (scores kept in log2 space)
#define QSCALE (0.088388347648318447f * 1.4426950408889634f)

typedef __attribute__((ext_vector_type(8))) short short8;
typedef __attribute__((ext_vector_type(4))) float f32x4;

// DPP-based wave64 sum; result valid in lane 63.
template<int CTRL, int RMASK>
__device__ __forceinline__ float dpp_add(float x) {
  int y = __builtin_amdgcn_update_dpp(0, __float_as_int(x), CTRL, RMASK, 0xf, true);
  return x + __int_as_float(y);
}
__device__ __forceinline__ float wave_sum63(float x) {
  x = dpp_add<0xB1,  0xf>(x);
  x = dpp_add<0x4E,  0xf>(x);
  x = dpp_add<0x141, 0xf>(x);
  x = dpp_add<0x140, 0xf>(x);
  x = dpp_add<0x142, 0xa>(x);
  x = dpp_add<0x143, 0xc>(x);
  return x;
}
__device__ __forceinline__ float bcast63(float x) {
  return __int_as_float(__builtin_amdgcn_readlane(__float_as_int(x), 63));
}

// DPP lane-permute mov (full row/bank masks, bound_ctrl=1)
template<int CTRL>
__device__ __forceinline__ float dpp_mov(float x) {
  return __int_as_float(
      __builtin_amdgcn_update_dpp(0, __float_as_int(x), CTRL, 0xf, 0xf, true));
}
template<int L>
__device__ __forceinline__ float rdlane(float x) {
  return __int_as_float(__builtin_amdgcn_readlane(__float_as_int(x), L));
}
// Crossed-select merge (verified on HW in R5).
template<int CTRL>
__device__ __forceinline__ float merge2(float z0, float z1, bool beta) {
  float keep = beta ? z1 : z0;
  float sel  = beta ? z0 : z1;
  return keep + dpp_mov<CTRL>(sel);
}
// Joint 2-key all-lane reduction; even lanes get key0's sum, odd key1's.
__device__ __forceinline__ float red2(float z0, float z1, bool b0) {
  float r = merge2<0xB1>(z0, z1, b0);   // quad_perm xor1 (crossed-select)
  r += dpp_mov<0x4E>(r);                // quad_perm xor2
  r += dpp_mov<0x124>(r);               // row_ror:4
  r += dpp_mov<0x128>(r);               // row_ror:8
  r += __shfl_xor(r, 16);
  r += __shfl_xor(r, 32);
  return r;
}

__device__ __forceinline__ unsigned short bfbits(float x) {
  __hip_bfloat16 h = __float2bfloat16(x);
  unsigned short u; __builtin_memcpy(&u, &h, 2); return u;
}
__device__ __forceinline__ float bf2f(unsigned short u) {
  return __uint_as_float(((unsigned)u) << 16);
}

// Split-bf16 pack of 8 floats (hi = truncation via v_perm, lo = exact
// residual rounded-ne) -- the verified A-fragment recipe.
__device__ __forceinline__ void packA(const float av[8], short8* ahi, short8* alo) {
  union { short8 v; unsigned u[4]; } hi, lo;
  #pragma unroll
  for (int j = 0; j < 4; j++) {
    unsigned b0u = __float_as_uint(av[2 * j]);
    unsigned b1u = __float_as_uint(av[2 * j + 1]);
    hi.u[j] = __builtin_amdgcn_perm(b1u, b0u, 0x07060302u);
    float l0 = av[2 * j]     - __uint_as_float(b0u & 0xFFFF0000u);
    float l1 = av[2 * j + 1] - __uint_as_float(b1u & 0xFFFF0000u);
    __hip_bfloat162 lp = __float22bfloat162_rn(make_float2(l0, l1));
    __builtin_memcpy(&lo.u[j], &lp, 4);
  }
  *ahi = hi.v; *alo = lo.v;
}

// One 16(M)x16-cols(cb)x128(K) split-bf16 MFMA unit: A from LDS rows
// [mt*16 + (lane&15)][k] (row stride 132 floats), B from packed planes.
__device__ __forceinline__ f32x4 mm16x128(
    const float* __restrict__ Abuf, int mt, int cb, int lane,
    const unsigned short* __restrict__ bhp,
    const unsigned short* __restrict__ blp)
{
  f32x4 acc = {0.f, 0.f, 0.f, 0.f};
  const float* arow = Abuf + (mt * 16 + (lane & 15)) * 132;
  #pragma unroll
  for (int kc = 0; kc < 4; kc++) {
    int kb = kc * 32 + (lane >> 4) * 8;
    float4 A0 = *(const float4*)(arow + kb);
    float4 A1 = *(const float4*)(arow + kb + 4);
    float av[8] = {A0.x, A0.y, A0.z, A0.w, A1.x, A1.y, A1.z, A1.w};
    short8 ahi, alo;
    packA(av, &ahi, &alo);
    int f = ((cb * 4 + kc) * 64 + lane) * 8;
    short8 bh = *(const short8*)(bhp + f);
    short8 bl = *(const short8*)(blp + f);
    acc = __builtin_amdgcn_mfma_f32_16x16x32_bf16(ahi, bh, acc, 0, 0, 0);
    acc = __builtin_amdgcn_mfma_f32_16x16x32_bf16(ahi, bl, acc, 0, 0, 0);
    acc = __builtin_amdgcn_mfma_f32_16x16x32_bf16(alo, bh, acc, 0, 0, 0);
  }
  return acc;
}

// Aux: pure weight packing (table machinery deleted -- time encoding is now
// computed via MFMA in the main kernel).
//  blocks 0..511 : em_w1 -> bf16 hi/lo planes (B-frag order, K=512)
//  blocks 512..639: w2^T -> planes (B[k=d][n=h] = tp_w2[n*H+k]), K=128
//  blocks 640..767: w2   -> planes (B[k=h][n=d] = tp_w2[k*H+n]), K=128
__global__ __launch_bounds__(128) void aux_kernel(
    const float* __restrict__ em_w1, const float* __restrict__ tp_w2,
    float* __restrict__ ws)
{
  int blk = blockIdx.x;
  int tid = threadIdx.x;
  if (blk < 512) {
    int idx = blk * 128 + tid;                     // 65536 total
    int j  = idx & 7;
    int l  = (idx >> 3) & 63;
    int kc = (idx >> 9) & 15;
    int c  = idx >> 13;
    int k = kc * 32 + ((l >> 4) * 8) + j;
    int n = c * 16 + (l & 15);
    float x = em_w1[k * H + n];
    unsigned short hb = bfbits(x);
    unsigned short lb = bfbits(x - bf2f(hb));
    ((unsigned short*)(ws + WSB_HI))[idx] = hb;
    ((unsigned short*)(ws + WSB_LO))[idx] = lb;
  } else {
    int base = (blk < 640) ? 512 : 640;
    int idx = (blk - base) * 128 + tid;            // 16384 total
    int j  = idx & 7;
    int l  = (idx >> 3) & 63;
    int kc = (idx >> 9) & 3;
    int c  = idx >> 11;
    int k = kc * 32 + ((l >> 4) * 8) + j;
    int n = c * 16 + (l & 15);
    float x = (blk < 640) ? tp_w2[n * H + k] : tp_w2[k * H + n];
    unsigned short hb = bfbits(x);
    unsigned short lb = bfbits(x - bf2f(hb));
    int off_hi = (blk < 640) ? W2T_HI : W2_HI;
    int off_lo = (blk < 640) ? W2T_LO : W2_LO;
    ((unsigned short*)(ws + off_hi))[idx] = hb;
    ((unsigned short*)(ws + off_lo))[idx] = lb;
  }
}

// Attention loop: table gathers REPLACED by on-the-fly h_k = relu(d*w1+b1)
// and the precomputed g = w2^T q (per side, 2 dims/lane from LDS buf).
// Per-iteration gather traffic: 8 emb loads only (was 8x1KB table + 8 emb).
// ONLINE-max log2-softmax unchanged; fallback (seeded mask, forced -1e9,
// ss=20 exact) unchanged. Outputs per side: z_fix (ne+sign part, normalized)
// into zbuf, y = sum(w*h)/ss into buf row (consumed by ZT MFMA epilogue).
__device__ __forceinline__ void run_sides(
    int eBase, int b0, int B, int lane,
    const int* __restrict__ edge_index, const int* __restrict__ edge_ts,
    const int* __restrict__ hist_nb, const int* __restrict__ hist_tm,
    const int* __restrict__ hist_sg,
    const float* __restrict__ node_emb,
    float w10, float w11, float b10, float b11,
    float2 se0, float2 se1,
    float* __restrict__ zbuf, float* __restrict__ buf)
{
  const float S = QSCALE;
  const bool b0sel = (lane & 1) != 0;
  // ---- prefetch edge eBase (both sides) ----
  int eN = b0 + eBase;
  int nU = edge_index[eN];
  int nV = edge_index[B + eN];
  int t_n = edge_ts[eN];
  float2 qU_n = *(const float2*)(node_emb + (size_t)nU * H + 2 * lane);
  float2 qV_n = *(const float2*)(node_emb + (size_t)nV * H + 2 * lane);
  int pkU_n = 0, tmU_n = 0, pkV_n = 0, tmV_n = 0;
  if (lane < K) {
    pkU_n = (hist_nb[nU * K + lane] << 1) | hist_sg[nU * K + lane];
    tmU_n = hist_tm[nU * K + lane];
    pkV_n = (hist_nb[nV * K + lane] << 1) | hist_sg[nV * K + lane];
    tmV_n = hist_tm[nV * K + lane];
  }

  #pragma unroll 1
  for (int p = 0; p < 4; p++) {
    int e = eBase + p;
    int tC = t_n;
    float2 qU = qU_n, qV = qV_n;
    int pkU = pkU_n, tmU = tmU_n, pkV = pkV_n, tmV = tmV_n;
    if (p < 3) {
      int e2 = b0 + e + 1;
      int nU2 = edge_index[e2];
      int nV2 = edge_index[B + e2];
      t_n = edge_ts[e2];
      qU_n = *(const float2*)(node_emb + (size_t)nU2 * H + 2 * lane);
      qV_n = *(const float2*)(node_emb + (size_t)nV2 * H + 2 * lane);
      if (lane < K) {
        pkU_n = (hist_nb[nU2 * K + lane] << 1) | hist_sg[nU2 * K + lane];
        tmU_n = hist_tm[nU2 * K + lane];
        pkV_n = (hist_nb[nV2 * K + lane] << 1) | hist_sg[nV2 * K + lane];
        tmV_n = hist_tm[nV2 * K + lane];
      }
    }

    // per-side g slices (2 dims/lane) from the G buffer
    float2 gU = *(const float2*)(buf + e * 132 + 2 * lane);
    float2 gV = *(const float2*)(buf + (16 + e) * 132 + 2 * lane);

    unsigned long long mU0 = __ballot((lane < K) && (tmU < tC) && (pkU >= 0));
    unsigned long long mV0 = __ballot((lane < K) && (tmV < tC) && (pkV >= 0));
    bool fU = (mU0 == 0), fV = (mV0 == 0);
    unsigned long long mU = fU ? 0xFFFFFull : mU0;
    unsigned long long mV = fV ? 0xFFFFFull : mV0;
    float qUx = qU.x * S, qUy = qU.y * S;
    float qVx = qV.x * S, qVy = qV.y * S;

    // per-side sign-embedding score constants (wave-uniform)
    float cseU0 = bcast63(wave_sum63(qUx * se0.x + qUy * se0.y));
    float cseU1 = bcast63(wave_sum63(qUx * se1.x + qUy * se1.y));
    float cseV0 = bcast63(wave_sum63(qVx * se0.x + qVy * se0.y));
    float cseV1 = bcast63(wave_sum63(qVx * se1.x + qVy * se1.y));

    float mxU = -3.0e38f, ssU = 0.f, s1U = 0.f;
    float zNU0 = 0.f, zNU1 = 0.f, yU0 = 0.f, yU1 = 0.f;
    float mxV = -3.0e38f, ssV = 0.f, s1V = 0.f;
    float zNV0 = 0.f, zNV1 = 0.f, yV0 = 0.f, yV1 = 0.f;

    while (mU | mV) {
      bool vUa = mU != 0; int kUa = vUa ? __ffsll((long long)mU) - 1 : 0; mU &= mU - 1;
      bool vUb = mU != 0; int kUb = vUb ? __ffsll((long long)mU) - 1 : 0; mU &= mU - 1;
      bool vUc = mU != 0; int kUc = vUc ? __ffsll((long long)mU) - 1 : 0; mU &= mU - 1;
      bool vUd = mU != 0; int kUd = vUd ? __ffsll((long long)mU) - 1 : 0; mU &= mU - 1;
      bool vVa = mV != 0; int kVa = vVa ? __ffsll((long long)mV) - 1 : 0; mV &= mV - 1;
      bool vVb = mV != 0; int kVb = vVb ? __ffsll((long long)mV) - 1 : 0; mV &= mV - 1;
      bool vVc = mV != 0; int kVc = vVc ? __ffsll((long long)mV) - 1 : 0; mV &= mV - 1;
      bool vVd = mV != 0; int kVd = vVd ? __ffsll((long long)mV) - 1 : 0; mV &= mV - 1;

      int tmUa = __builtin_amdgcn_readlane(tmU, kUa), pkUa = __builtin_amdgcn_readlane(pkU, kUa);
      int tmUb = __builtin_amdgcn_readlane(tmU, kUb), pkUb = __builtin_amdgcn_readlane(pkU, kUb);
      int tmUc = __builtin_amdgcn_readlane(tmU, kUc), pkUc = __builtin_amdgcn_readlane(pkU, kUc);
      int tmUd = __builtin_amdgcn_readlane(tmU, kUd), pkUd = __builtin_amdgcn_readlane(pkU, kUd);
      int tmVa = __builtin_amdgcn_readlane(tmV, kVa), pkVa = __builtin_amdgcn_readlane(pkV, kVa);
      int tmVb = __builtin_amdgcn_readlane(tmV, kVb), pkVb = __builtin_amdgcn_readlane(pkV, kVb);
      int tmVc = __builtin_amdgcn_readlane(tmV, kVc), pkVc = __builtin_amdgcn_readlane(pkV, kVc);
      int tmVd = __builtin_amdgcn_readlane(tmV, kVd), pkVd = __builtin_amdgcn_readlane(pkV, kVd);

      float dUa = (float)(tC - tmUa), dUb = (float)(tC - tmUb);
      float dUc = (float)(tC - tmUc), dUd = (float)(tC - tmUd);
      float dVa = (float)(tC - tmVa), dVb = (float)(tC - tmVb);
      float dVc = (float)(tC - tmVc), dVd = (float)(tC - tmVd);

      // ---- 8 emb gathers (the only remaining per-key memory traffic)
      float2 neUa = *(const float2*)(node_emb + (size_t)(pkUa >> 1) * H + 2 * lane);
      float2 neUb = *(const float2*)(node_emb + (size_t)(pkUb >> 1) * H + 2 * lane);
      float2 neUc = *(const float2*)(node_emb + (size_t)(pkUc >> 1) * H + 2 * lane);
      float2 neUd = *(const float2*)(node_emb + (size_t)(pkUd >> 1) * H + 2 * lane);
      float2 neVa = *(const float2*)(node_emb + (size_t)(pkVa >> 1) * H + 2 * lane);
      float2 neVb = *(const float2*)(node_emb + (size_t)(pkVb >> 1) * H + 2 * lane);
      float2 neVc = *(const float2*)(node_emb + (size_t)(pkVc >> 1) * H + 2 * lane);
      float2 neVd = *(const float2*)(node_emb + (size_t)(pkVd >> 1) * H + 2 * lane);
      __builtin_amdgcn_sched_barrier(0);

      // ---- time-encoding h = relu(d*w1+b1), 2 dims/lane (replaces table)
      float hUa0 = fmaxf(dUa * w10 + b10, 0.f), hUa1 = fmaxf(dUa * w11 + b11, 0.f);
      float hUb0 = fmaxf(dUb * w10 + b10, 0.f), hUb1 = fmaxf(dUb * w11 + b11, 0.f);
      float hUc0 = fmaxf(dUc * w10 + b10, 0.f), hUc1 = fmaxf(dUc * w11 + b11, 0.f);
      float hUd0 = fmaxf(dUd * w10 + b10, 0.f), hUd1 = fmaxf(dUd * w11 + b11, 0.f);
      float hVa0 = fmaxf(dVa * w10 + b10, 0.f), hVa1 = fmaxf(dVa * w11 + b11, 0.f);
      float hVb0 = fmaxf(dVb * w10 + b10, 0.f), hVb1 = fmaxf(dVb * w11 + b11, 0.f);
      float hVc0 = fmaxf(dVc * w10 + b10, 0.f), hVc1 = fmaxf(dVc * w11 + b11, 0.f);
      float hVd0 = fmaxf(dVd * w10 + b10, 0.f), hVd1 = fmaxf(dVd * w11 + b11, 0.f);

      // ---- score partials: q·ne + h·g  (q pre-scaled; g built from scaled q)
      float p0 = qUx * neUa.x + qUy * neUa.y + hUa0 * gU.x + hUa1 * gU.y;
      float p1 = qUx * neUb.x + qUy * neUb.y + hUb0 * gU.x + hUb1 * gU.y;
      float p2 = qUx * neUc.x + qUy * neUc.y + hUc0 * gU.x + hUc1 * gU.y;
      float p3 = qUx * neUd.x + qUy * neUd.y + hUd0 * gU.x + hUd1 * gU.y;
      float p4 = qVx * neVa.x + qVy * neVa.y + hVa0 * gV.x + hVa1 * gV.y;
      float p5 = qVx * neVb.x + qVy * neVb.y + hVb0 * gV.x + hVb1 * gV.y;
      float p6 = qVx * neVc.x + qVy * neVc.y + hVc0 * gV.x + hVc1 * gV.y;
      float p7 = qVx * neVd.x + qVy * neVd.y + hVd0 * gV.x + hVd1 * gV.y;
      float cU01 = red2(p0, p1, b0sel);
      float cU23 = red2(p2, p3, b0sel);
      float cV01 = red2(p4, p5, b0sel);
      float cV23 = red2(p6, p7, b0sel);

      float sUa = vUa ? (fU ? -1e9f : (rdlane<0>(cU01) + ((pkUa & 1) ? cseU1 : cseU0))) : -3.0e38f;
      float sUb = vUb ? (fU ? -1e9f : (rdlane<1>(cU01) + ((pkUb & 1) ? cseU1 : cseU0))) : -3.0e38f;
      float sUc = vUc ? (fU ? -1e9f : (rdlane<0>(cU23) + ((pkUc & 1) ? cseU1 : cseU0))) : -3.0e38f;
      float sUd = vUd ? (fU ? -1e9f : (rdlane<1>(cU23) + ((pkUd & 1) ? cseU1 : cseU0))) : -3.0e38f;
      float sVa = vVa ? (fV ? -1e9f : (rdlane<0>(cV01) + ((pkVa & 1) ? cseV1 : cseV0))) : -3.0e38f;
      float sVb = vVb ? (fV ? -1e9f : (rdlane<1>(cV01) + ((pkVb & 1) ? cseV1 : cseV0))) : -3.0e38f;
      float sVc = vVc ? (fV ? -1e9f : (rdlane<0>(cV23) + ((pkVc & 1) ? cseV1 : cseV0))) : -3.0e38f;
      float sVd = vVd ? (fV ? -1e9f : (rdlane<1>(cV23) + ((pkVd & 1) ? cseV1 : cseV0))) : -3.0e38f;

      // ---- 4-wide online-max softmax accumulate (log2 space)
      float mnU = fmaxf(fmaxf(mxU, fmaxf(sUa, sUb)), fmaxf(sUc, sUd));
      float alU = exp2f(mxU - mnU);
      float wUa = exp2f(sUa - mnU), wUb = exp2f(sUb - mnU);
      float wUc = exp2f(sUc - mnU), wUd = exp2f(sUd - mnU);
      ssU = ssU * alU + ((wUa + wUb) + (wUc + wUd));
      s1U = s1U * alU + ((((pkUa & 1) ? wUa : 0.f) + ((pkUb & 1) ? wUb : 0.f))
                       + (((pkUc & 1) ? wUc : 0.f) + ((pkUd & 1) ? wUd : 0.f)));
      zNU0 = zNU0 * alU + ((wUa * neUa.x + wUb * neUb.x) + (wUc * neUc.x + wUd * neUd.x));
      zNU1 = zNU1 * alU + ((wUa * neUa.y + wUb * neUb.y) + (wUc * neUc.y + wUd * neUd.y));
      yU0  = yU0  * alU + ((wUa * hUa0 + wUb * hUb0) + (wUc * hUc0 + wUd * hUd0));
      yU1  = yU1  * alU + ((wUa * hUa1 + wUb * hUb1) + (wUc * hUc1 + wUd * hUd1));
      mxU = mnU;

      float mnV = fmaxf(fmaxf(mxV, fmaxf(sVa, sVb)), fmaxf(sVc, sVd));
      float alV = exp2f(mxV - mnV);
      float wVa = exp2f(sVa - mnV), wVb = exp2f(sVb - mnV);
      float wVc = exp2f(sVc - mnV), wVd = exp2f(sVd - mnV);
      ssV = ssV * alV + ((wVa + wVb) + (wVc + wVd));
      s1V = s1V * alV + ((((pkVa & 1) ? wVa : 0.f) + ((pkVb & 1) ? wVb : 0.f))
                       + (((pkVc & 1) ? wVc : 0.f) + ((pkVd & 1) ? wVd : 0.f)));
      zNV0 = zNV0 * alV + ((wVa * neVa.x + wVb * neVb.x) + (wVc * neVc.x + wVd * neVd.x));
      zNV1 = zNV1 * alV + ((wVa * neVa.y + wVb * neVb.y) + (wVc * neVc.y + wVd * neVd.y));
      yV0  = yV0  * alV + ((wVa * hVa0 + wVb * hVb0) + (wVc * hVc0 + wVd * hVd0));
      yV1  = yV1  * alV + ((wVa * hVa1 + wVb * hVb1) + (wVc * hVc1 + wVd * hVd1));
      mxV = mnV;
    }

    // normalize; fallback sides have ss == 20 exactly
    float invU = 1.f / ssU;
    float r1U = s1U * invU, r0U = 1.f - r1U;
    float zf0 = zNU0 * invU + r0U * se0.x + r1U * se1.x;
    float zf1 = zNU1 * invU + r0U * se0.y + r1U * se1.y;
    float invV = 1.f / ssV;
    float r1V = s1V * invV, r0V = 1.f - r1V;
    float zg0 = zNV0 * invV + r0V * se0.x + r1V * se1.x;
    float zg1 = zNV1 * invV + r0V * se0.y + r1V * se1.y;

    int sw = (e & 7) << 1;
    int ccU = lane ^ sw;
    int ccV = (64 + lane) ^ sw;
    *(float2*)&zbuf[(e << 8) + (ccU << 1)] = make_float2(zf0, zf1);
    *(float2*)&zbuf[(e << 8) + (ccV << 1)] = make_float2(zg0, zg1);
    // y rows (overwrite this edge's g rows -- already consumed)
    *(float2*)(buf + e * 132 + 2 * lane)        = make_float2(yU0 * invU, yU1 * invU);
    *(float2*)(buf + (16 + e) * 132 + 2 * lane) = make_float2(yV0 * invV, yV1 * invV);
  }
}

// Main fused kernel. Phases:
//  Q-stage -> G = Qs @ w2^T (MFMA) -> attention loop (emb gathers only)
//  -> ZT = Y @ w2 (MFMA, added into zbuf) -> MLP layer1 (MFMA) -> layer2.
// LDS: zbuf 16KB + buf (q/G/Y, 32x132) 16.5KB = ~33KB -> 4 blocks/CU.
__global__ __launch_bounds__(256, 4) void tgat_main_kernel(
    const int* __restrict__ edge_index, const int* __restrict__ edge_ts,
    const int* __restrict__ hist_nb, const int* __restrict__ hist_tm,
    const int* __restrict__ hist_sg,
    const float* __restrict__ node_emb, const float* __restrict__ sign_emb,
    const float* __restrict__ tp_w1, const float* __restrict__ tp_b1,
    const float* __restrict__ em_b1,
    const float* __restrict__ em_w2, const float* __restrict__ em_b2,
    const float* __restrict__ ws, float* __restrict__ out, int B)
{
  __shared__ __align__(16) float zbuf[EPB * 256];   // 16 KB
  __shared__ __align__(16) float buf[32 * 132];     // 16.5 KB: q -> G -> Y

  int tid = threadIdx.x;
  int lane = tid & 63;
  int wv = __builtin_amdgcn_readfirstlane(tid >> 6);
  int b0 = blockIdx.x * EPB;

  float2 se0 = *(const float2*)(sign_emb + 2 * lane);
  float2 se1 = *(const float2*)(sign_emb + H + 2 * lane);
  float w10 = tp_w1[2 * lane], w11 = tp_w1[2 * lane + 1];
  float b10 = tp_b1[2 * lane], b11 = tp_b1[2 * lane + 1];

  // ---- Q-stage: scaled q rows (U: rows 0-15, V: rows 16-31)
  int eBase = wv * 4;
  #pragma unroll
  for (int p = 0; p < 4; p++) {
    int e = eBase + p;
    int eg = b0 + e;
    int nU = edge_index[eg];
    int nV = edge_index[B + eg];
    float2 qU = *(const float2*)(node_emb + (size_t)nU * H + 2 * lane);
    float2 qV = *(const float2*)(node_emb + (size_t)nV * H + 2 * lane);
    *(float2*)(buf + e * 132 + 2 * lane) =
        make_float2(qU.x * QSCALE, qU.y * QSCALE);
    *(float2*)(buf + (16 + e) * 132 + 2 * lane) =
        make_float2(qV.x * QSCALE, qV.y * QSCALE);
  }
  __syncthreads();

  // ---- G = Qs @ w2^T : wave wv covers col-blocks wv*2, wv*2+1; both M-tiles
  const unsigned short* w2t_hi = (const unsigned short*)(ws + W2T_HI);
  const unsigned short* w2t_lo = (const unsigned short*)(ws + W2T_LO);
  int cbA = wv * 2, cbB = wv * 2 + 1;
  f32x4 g0 = mm16x128(buf, 0, cbA, lane, w2t_hi, w2t_lo);
  f32x4 g1 = mm16x128(buf, 1, cbA, lane, w2t_hi, w2t_lo);
  f32x4 g2 = mm16x128(buf, 0, cbB, lane, w2t_hi, w2t_lo);
  f32x4 g3 = mm16x128(buf, 1, cbB, lane, w2t_hi, w2t_lo);
  __syncthreads();   // all A-reads of q done before overwrite with G
  {
    int rb = (lane >> 4) * 4;
    int cl = lane & 15;
    #pragma unroll
    for (int r = 0; r < 4; r++) {
      buf[(rb + r) * 132      + cbA * 16 + cl] = g0[r];
      buf[(16 + rb + r) * 132 + cbA * 16 + cl] = g1[r];
      buf[(rb + r) * 132      + cbB * 16 + cl] = g2[r];
      buf[(16 + rb + r) * 132 + cbB * 16 + cl] = g3[r];
    }
  }
  __syncthreads();

  // ---- attention loop (reads g slices; writes z_fix to zbuf, y to buf)
  run_sides(eBase, b0, B, lane, edge_index, edge_ts, hist_nb, hist_tm,
            hist_sg, node_emb, w10, w11, b10, b11, se0, se1, zbuf, buf);
  __syncthreads();

  // ---- ZT = Y @ w2, accumulated into zbuf (z = z_fix + ZT)
  const unsigned short* w2_hi = (const unsigned short*)(ws + W2_HI);
  const unsigned short* w2_lo = (const unsigned short*)(ws + W2_LO);
  f32x4 z0 = mm16x128(buf, 0, cbA, lane, w2_hi, w2_lo);
  f32x4 z1 = mm16x128(buf, 1, cbA, lane, w2_hi, w2_lo);
  f32x4 z2 = mm16x128(buf, 0, cbB, lane, w2_hi, w2_lo);
  f32x4 z3 = mm16x128(buf, 1, cbB, lane, w2_hi, w2_lo);
  {
    int rb = (lane >> 4) * 4;
    int cl = lane & 15;
    #pragma unroll
    for (int r = 0; r < 4; r++) {
      int e0 = rb + r;                       // U rows
      int sw0 = (e0 & 7) << 1;
      int dA = cbA * 16 + cl;                // U: d in [0,128)
      int dB = cbB * 16 + cl;
      zbuf[(e0 << 8) + ((((dA >> 1)) ^ sw0) << 1) + (dA & 1)] += z0[r];
      zbuf[(e0 << 8) + ((((dB >> 1)) ^ sw0) << 1) + (dB & 1)] += z2[r];
      int dA2 = 128 + dA, dB2 = 128 + dB;    // V: d in [128,256)
      zbuf[(e0 << 8) + ((((dA2 >> 1)) ^ sw0) << 1) + (dA2 & 1)] += z1[r];
      zbuf[(e0 << 8) + ((((dB2 >> 1)) ^ sw0) << 1) + (dB2 & 1)] += z3[r];
    }
  }
  __syncthreads();

  // ---- MLP layer 1 via split-bf16 MFMA: hid[16][128] = feat[16][512] @ em_w1
  const unsigned short* whi = (const unsigned short*)(ws + WSB_HI);
  const unsigned short* wlo = (const unsigned short*)(ws + WSB_LO);
  int c0 = 2 * wv;
  int m_ = lane & 15;
  int qd = lane >> 4;
  int sw = (m_ & 7) << 1;
  const float* zrow = zbuf + (m_ << 8);
  f32x4 acc0 = {0.f, 0.f, 0.f, 0.f};
  f32x4 acc1 = {0.f, 0.f, 0.f, 0.f};
  #pragma unroll
  for (int kc = 0; kc < 16; kc++) {
    const int reg = kc >> 2;
    int cb = (kc & 3) * 16 + qd * 4;
    float av[8];
    if (reg == 0) {
      float4 A0 = *(const float4*)(zrow + (((cb    ) ^ sw) << 1));
      float4 A1 = *(const float4*)(zrow + (((cb + 2) ^ sw) << 1));
      av[0]=A0.x; av[1]=A0.y; av[2]=A0.z; av[3]=A0.w;
      av[4]=A1.x; av[5]=A1.y; av[6]=A1.z; av[7]=A1.w;
    } else if (reg == 1) {
      float4 A0 = *(const float4*)(zrow + (((cb + 64) ^ sw) << 1));
      float4 A1 = *(const float4*)(zrow + (((cb + 66) ^ sw) << 1));
      av[0]=A0.x; av[1]=A0.y; av[2]=A0.z; av[3]=A0.w;
      av[4]=A1.x; av[5]=A1.y; av[6]=A1.z; av[7]=A1.w;
    } else {
      float4 U0 = *(const float4*)(zrow + (((cb    ) ^ sw) << 1));
      float4 U1 = *(const float4*)(zrow + (((cb + 2) ^ sw) << 1));
      float4 V0 = *(const float4*)(zrow + (((cb + 64) ^ sw) << 1));
      float4 V1 = *(const float4*)(zrow + (((cb + 66) ^ sw) << 1));
      float uu[8] = {U0.x,U0.y,U0.z,U0.w,U1.x,U1.y,U1.z,U1.w};
      float vvv[8] = {V0.x,V0.y,V0.z,V0.w,V1.x,V1.y,V1.z,V1.w};
      if (reg == 2) {
        #pragma unroll
        for (int j = 0; j < 8; j++) av[j] = fabsf(uu[j] - vvv[j]);
      } else {
        #pragma unroll
        for (int j = 0; j < 8; j++) av[j] = uu[j] * vvv[j];
      }
    }
    short8 ahi, alo;
    packA(av, &ahi, &alo);
    int f0 = (((c0    ) * 16 + kc) * 64 + lane) * 8;
    int f1 = (((c0 + 1) * 16 + kc) * 64 + lane) * 8;
    short8 bh0 = *(const short8*)(whi + f0);
    short8 bl0 = *(const short8*)(wlo + f0);
    short8 bh1 = *(const short8*)(whi + f1);
    short8 bl1 = *(const short8*)(wlo + f1);
    acc0 = __builtin_amdgcn_mfma_f32_16x16x32_bf16(ahi, bh0, acc0, 0, 0, 0);
    acc0 = __builtin_amdgcn_mfma_f32_16x16x32_bf16(ahi, bl0, acc0, 0, 0, 0);
    acc0 = __builtin_amdgcn_mfma_f32_16x16x32_bf16(alo, bh0, acc0, 0, 0, 0);
    acc1 = __builtin_amdgcn_mfma_f32_16x16x32_bf16(ahi, bh1, acc1, 0, 0, 0);
    acc1 = __builtin_amdgcn_mfma_f32_16x16x32_bf16(ahi, bl1, acc1, 0, 0, 0);
    acc1 = __builtin_amdgcn_mfma_f32_16x16x32_bf16(alo, bh1, acc1, 0, 0, 0);
  }
  __syncthreads();   // all A-reads of zbuf complete before overlay reuse

  // bias + relu, write hid into zbuf overlay (stride 132)
  float* hp = zbuf;
  float eb0 = em_b1[c0 * 16 + m_];
  float eb1 = em_b1[(c0 + 1) * 16 + m_];
  #pragma unroll
  for (int r = 0; r < 4; r++) {
    int edge = qd * 4 + r;
    hp[edge * 132 + c0 * 16 + m_]       = fmaxf(acc0[r] + eb0, 0.f);
    hp[edge * 132 + (c0 + 1) * 16 + m_] = fmaxf(acc1[r] + eb1, 0.f);
  }
  __syncthreads();

  // ---- layer 2: logits = hid @ em_w2 + em_b2
  float2 w2v = *(const float2*)(em_w2 + 2 * lane);
  float bias2 = em_b2[0];
  #pragma unroll
  for (int i = 0; i < 4; i++) {
    int e = wv * 4 + i;
    int b = b0 + e;
    float2 hv = *(const float2*)(hp + e * 132 + 2 * lane);
    float p = wave_sum63(hv.x * w2v.x + hv.y * w2v.y);
    float ps = bcast63(p);
    if (lane == 0 && b < B) out[b] = ps + bias2;
  }
}

extern "C" void kernel_launch(void* const* d_in, const int* in_sizes, int n_in,
                              void* d_out, int out_size, void* d_ws, size_t ws_size,
                              hipStream_t stream)
{
  (void)n_in; (void)out_size; (void)ws_size;
  const int* edge_index = (const int*)d_in[0];
  const int* edge_ts    = (const int*)d_in[1];
  const int* hist_nb    = (const int*)d_in[2];
  const int* hist_tm    = (const int*)d_in[3];
  const int* hist_sg    = (const int*)d_in[4];
  const float* node_emb = (const float*)d_in[5];
  const float* sign_emb = (const float*)d_in[6];
  const float* tp_w1    = (const float*)d_in[7];
  const float* tp_b1    = (const float*)d_in[8];
  const float* tp_w2    = (const float*)d_in[9];
  const float* tp_b2    = (const float*)d_in[10];
  const float* em_w1    = (const float*)d_in[11];
  const float* em_b1    = (const float*)d_in[12];
  const float* em_w2    = (const float*)d_in[13];
  const float* em_b2    = (const float*)d_in[14];
  (void)tp_b2;
  float* out = (float*)d_out;
  float* ws  = (float*)d_ws;
  int B = in_sizes[1];

  hipLaunchKernelGGL(aux_kernel, dim3(768), dim3(128), 0, stream,
                     em_w1, tp_w2, ws);
  int grid = (B + EPB - 1) / EPB;
  hipLaunchKernelGGL(tgat_main_kernel, dim3(grid), dim3(256), 0, stream,
                     edge_index, edge_ts, hist_nb, hist_tm, hist_sg,
                     node_emb, sign_emb, tp_w1, tp_b1, em_b1, em_w2, em_b2,
                     ws, out, B);
}